// Round 1
// 191.113 us; speedup vs baseline: 1.0198x; 1.0198x over previous
//
#include <hip/hip_runtime.h>
#include <math.h>

// Problem constants (HybridAttention): B=2, S=2048, E=1024, H=16, Dk=64
constexpr int Ec  = 1024;
constexpr int Hc  = 16;
constexpr int DKc = 64;
constexpr int Bc  = 2;
constexpr int Sc  = 2048;
constexpr int Mc  = Bc * Sc;  // 4096 rows total

typedef _Float16 half8 __attribute__((ext_vector_type(8)));
typedef _Float16 half4 __attribute__((ext_vector_type(4)));
typedef float    floatx4 __attribute__((ext_vector_type(4)));

#define MFMA16(a, b, c) __builtin_amdgcn_mfma_f32_16x16x32_f16(a, b, c, 0, 0, 0)

// async 16B global->LDS (dest = wave-uniform base + lane*16)
__device__ __forceinline__ void async_lds16(const _Float16* g, _Float16* l)
{
    __builtin_amdgcn_global_load_lds(
        (const __attribute__((address_space(1))) unsigned int*)g,
        (__attribute__((address_space(3))) unsigned int*)l, 16, 0, 0);
}

// ---------------------------------------------------------------------------
// fp32 -> fp16 convert: x (4M) | Wq | Wk | Wv | Wo (1M each) into one fp16 pool
// ---------------------------------------------------------------------------
__global__ __launch_bounds__(256)
void convert_to_h(const float4* __restrict__ x,
                  const float4* __restrict__ wq,
                  const float4* __restrict__ wk,
                  const float4* __restrict__ wv,
                  const float4* __restrict__ wo,
                  half4* __restrict__ dst)
{
    const int i = blockIdx.x * 256 + threadIdx.x;   // 0 .. 2M-1 (float4 units)
    const float4* src; int off;
    if      (i < 1048576) { src = x;  off = i; }
    else if (i < 1310720) { src = wq; off = i - 1048576; }
    else if (i < 1572864) { src = wk; off = i - 1310720; }
    else if (i < 1835008) { src = wv; off = i - 1572864; }
    else                  { src = wo; off = i - 1835008; }
    const float4 v = src[off];
    half4 o;
    o.x = (_Float16)v.x; o.y = (_Float16)v.y;
    o.z = (_Float16)v.z; o.w = (_Float16)v.w;
    dst[i] = o;
}

// ---------------------------------------------------------------------------
// fp16 MFMA GEMM core v2: C[128x128] = A[M,K] * W[N,K]^T tile, BK=64.
// Chunk-XOR swizzle on the per-lane GLOBAL address keeps global_load_lds's
// contiguous lane*16 dest while making frag reads conflict-free.
// ---------------------------------------------------------------------------
__device__ __forceinline__ void mfma_gemm_core64(const _Float16* __restrict__ A,
                                                 const _Float16* __restrict__ Bw,
                                                 int m0, int n0,
                                                 _Float16* As, _Float16* Bs,
                                                 floatx4 acc[4][4])
{
    const int tid  = threadIdx.x;
    const int wave = tid >> 6, lane = tid & 63;
    const int l16  = lane & 15, quad = lane >> 4;
    const int wrow = (wave >> 1) * 64, wcol = (wave & 1) * 64;

    const int srow8  = lane >> 3;
    const int schunk = (lane & 7) ^ (srow8 & 7);
    const _Float16* ga = A  + (size_t)(m0 + wave * 32 + srow8) * Ec + schunk * 8;
    const _Float16* gb = Bw + (size_t)(n0 + wave * 32 + srow8) * Ec + schunk * 8;
    _Float16* lA = As + (size_t)(wave * 32) * 64;
    _Float16* lB = Bs + (size_t)(wave * 32) * 64;

    for (int kt = 0; kt < Ec; kt += 64) {
#pragma unroll
        for (int c = 0; c < 4; ++c) {
            async_lds16(ga + (size_t)(c * 8) * Ec + kt, lA + c * 512);
            async_lds16(gb + (size_t)(c * 8) * Ec + kt, lB + c * 512);
        }
        __syncthreads();

        half8 af[4][2], bf[4][2];
#pragma unroll
        for (int i = 0; i < 4; ++i) {
            const int ra = wrow + i * 16 + l16;
            const int rb = wcol + i * 16 + l16;
#pragma unroll
            for (int kc = 0; kc < 2; ++kc) {
                af[i][kc] = *(const half8*)&As[ra * 64 + (((quad + kc * 4) ^ (ra & 7)) * 8)];
                bf[i][kc] = *(const half8*)&Bs[rb * 64 + (((quad + kc * 4) ^ (rb & 7)) * 8)];
            }
        }
#pragma unroll
        for (int i = 0; i < 4; ++i)
#pragma unroll
            for (int j = 0; j < 4; ++j) {
                acc[i][j] = MFMA16(af[i][0], bf[j][0], acc[i][j]);
                acc[i][j] = MFMA16(af[i][1], bf[j][1], acc[i][j]);
            }
        __syncthreads();
    }
}

// QKV projection: z=0 -> Qh (pre-scaled by 1/8 * log2(e) so flash can use raw
// v_exp_f32/exp2 with no per-score multiply), z=1 -> Kh, z=2 -> V^T [B,H,Dk,S]
__global__ __launch_bounds__(256)
void gemm_qkv_mfma(const _Float16* __restrict__ xh,
                   const _Float16* __restrict__ wqh,
                   const _Float16* __restrict__ wkh,
                   const _Float16* __restrict__ wvh,
                   _Float16* __restrict__ Qh,
                   _Float16* __restrict__ Kh,
                   _Float16* __restrict__ VTh)
{
    __shared__ __align__(16) _Float16 As[128 * 64];
    __shared__ __align__(16) _Float16 Bs[128 * 64];
    const int z = blockIdx.z;
    const _Float16* W = (z == 0) ? wqh : (z == 1) ? wkh : wvh;
    const int m0 = blockIdx.y * 128, n0 = blockIdx.x * 128;

    floatx4 acc[4][4] = {};
    mfma_gemm_core64(xh, W, m0, n0, As, Bs, acc);

    const int tid  = threadIdx.x;
    const int wave = tid >> 6, lane = tid & 63;
    const int l16  = lane & 15, quad = lane >> 4;
    const int wrow = (wave >> 1) * 64, wcol = (wave & 1) * 64;

    if (z == 2) {
        // VT[((b*H+h)*Dk+d)*S + s]: 4 consecutive m (=s) per lane -> half4 store
#pragma unroll
        for (int i = 0; i < 4; ++i)
#pragma unroll
            for (int j = 0; j < 4; ++j) {
                const int n  = n0 + wcol + j * 16 + l16;
                const int hh = n >> 6, d = n & 63;
                const int mb = m0 + wrow + i * 16 + quad * 4;
                const int bb = mb >> 11, s = mb & (Sc - 1);
                half4 pk;
#pragma unroll
                for (int r = 0; r < 4; ++r) pk[r] = (_Float16)acc[i][j][r];
                *(half4*)&VTh[((size_t)((bb * Hc + hh) * DKc + d)) * Sc + s] = pk;
            }
    } else {
        _Float16* out = (z == 0) ? Qh : Kh;
        // 0.125 * log2(e): scores come out in log2 domain for exp2 softmax
        const float scale = (z == 0) ? 0.18033688011112042f : 1.0f;
#pragma unroll
        for (int i = 0; i < 4; ++i)
#pragma unroll
            for (int j = 0; j < 4; ++j) {
                const int n = n0 + wcol + j * 16 + l16;
#pragma unroll
                for (int r = 0; r < 4; ++r) {
                    const int m = m0 + wrow + i * 16 + quad * 4 + r;
                    out[(size_t)m * Ec + n] = (_Float16)(acc[i][j][r] * scale);
                }
            }
    }
}

// Output projection: fp16 A (mix), fp16 Wo, fp32 out. 128x64 tile, BK=64.
__global__ __launch_bounds__(256)
void gemm_out_mfma(const _Float16* __restrict__ A,
                   const _Float16* __restrict__ W,
                   float* __restrict__ C)
{
    __shared__ __align__(16) _Float16 As[128 * 64];
    __shared__ __align__(16) _Float16 Bs[64 * 64];
    const int m0 = blockIdx.y * 128, n0 = blockIdx.x * 64;

    const int tid  = threadIdx.x;
    const int wave = tid >> 6, lane = tid & 63;
    const int l16  = lane & 15, quad = lane >> 4;
    const int wrow = (wave >> 1) * 64, wcol = (wave & 1) * 32;

    const int srow8  = lane >> 3;
    const int schunk = (lane & 7) ^ (srow8 & 7);
    const _Float16* ga = A + (size_t)(m0 + wave * 32 + srow8) * Ec + schunk * 8;
    const _Float16* gb = W + (size_t)(n0 + wave * 16 + srow8) * Ec + schunk * 8;
    _Float16* lA = As + (size_t)(wave * 32) * 64;
    _Float16* lB = Bs + (size_t)(wave * 16) * 64;

    floatx4 acc[4][2] = {};

    for (int kt = 0; kt < Ec; kt += 64) {
#pragma unroll
        for (int c = 0; c < 4; ++c)
            async_lds16(ga + (size_t)(c * 8) * Ec + kt, lA + c * 512);
#pragma unroll
        for (int c = 0; c < 2; ++c)
            async_lds16(gb + (size_t)(c * 8) * Ec + kt, lB + c * 512);
        __syncthreads();

        half8 af[4][2], bf[2][2];
#pragma unroll
        for (int i = 0; i < 4; ++i) {
            const int ra = wrow + i * 16 + l16;
#pragma unroll
            for (int kc = 0; kc < 2; ++kc)
                af[i][kc] = *(const half8*)&As[ra * 64 + (((quad + kc * 4) ^ (ra & 7)) * 8)];
        }
#pragma unroll
        for (int j = 0; j < 2; ++j) {
            const int rb = wcol + j * 16 + l16;
#pragma unroll
            for (int kc = 0; kc < 2; ++kc)
                bf[j][kc] = *(const half8*)&Bs[rb * 64 + (((quad + kc * 4) ^ (rb & 7)) * 8)];
        }
#pragma unroll
        for (int i = 0; i < 4; ++i)
#pragma unroll
            for (int j = 0; j < 2; ++j) {
                acc[i][j] = MFMA16(af[i][0], bf[j][0], acc[i][j]);
                acc[i][j] = MFMA16(af[i][1], bf[j][1], acc[i][j]);
            }
        __syncthreads();
    }

#pragma unroll
    for (int i = 0; i < 4; ++i)
#pragma unroll
        for (int j = 0; j < 2; ++j) {
            const int n = n0 + wcol + j * 16 + l16;
#pragma unroll
            for (int r = 0; r < 4; ++r) {
                const int m = m0 + wrow + i * 16 + quad * 4 + r;
                C[(size_t)m * Ec + n] = acc[i][j][r];
            }
        }
}

// ---------------------------------------------------------------------------
// Flash attention v2: split-KV inside the block.
// 512 threads = two 4-wave groups; group g owns KV half g (16 tiles each)
// with private Kt/Vt/Ps buffers. LDS 74 KB -> 2 blocks/CU -> 16 waves/CU
// (was 8: occupancy was grid-capped at 2 waves/SIMD, MfmaUtil 24 / VALU 43
// both unsaturated = latency-bound). Keeps 32 q-rows/wave so K/V-fragment
// LDS reads per unit work are unchanged (BM=64 would double them).
// No-max softmax => partials combine by pure addition: group 1 dumps its
// O-acc + row sums to LDS (reusing dead K/V space), group 0 adds, normalizes,
// applies sin-mix, stores. exp2-domain scores (log2e folded into Q scale).
// ---------------------------------------------------------------------------
__global__ __launch_bounds__(512)
void flash_attn(const _Float16* __restrict__ Qh,
                const _Float16* __restrict__ Kh,
                const _Float16* __restrict__ VTh,
                const float* __restrict__ qw,
                _Float16* __restrict__ Mixh)
{
    constexpr int BM = 128, BN = 64, LDH = 72;
    constexpr int NT = (Sc / BN) / 2;                     // 16 tiles per group
    __shared__ __align__(16) _Float16 KVs[2][2][BN][LDH]; // [g][0=K,1=V] 36.9KB
    __shared__ __align__(16) _Float16 Ps[2][BM][LDH];     // 36.9KB
    __shared__ float Ls[BM];                              // group-1 row sums

    const int tid  = threadIdx.x;
    const int g    = tid >> 8;           // KV-half group
    const int wl   = (tid >> 6) & 3;     // wave within group
    const int lane = tid & 63;
    const int quad = lane >> 4, l16 = lane & 15;
    const int q0 = blockIdx.x * BM;
    const int bh = blockIdx.y;
    const int h  = bh & (Hc - 1), b = bh >> 4;

    _Float16 (*Kt)[LDH] = KVs[g][0];
    _Float16 (*Vt)[LDH] = KVs[g][1];
    _Float16 (*Pt)[LDH] = Ps[g];

    // Q fragments (usable as A- or B-operand: same lane->element map)
    half8 aq[2][2];
#pragma unroll
    for (int u = 0; u < 2; ++u) {
        const _Float16* qp = Qh + (size_t)(b * Sc + q0 + wl * 32 + u * 16 + l16) * Ec
                                + h * DKc + quad * 8;
        aq[u][0] = *(const half8*)qp;
        aq[u][1] = *(const half8*)(qp + 32);
    }

    // staging: 256 threads per group cover 64 rows x 64 halves
    const int tl   = tid & 255;
    const int srow = tl >> 2;
    const int sseg = (tl & 3) * 16;
    const _Float16* Kg = Kh + (size_t)(b * Sc + g * (Sc / 2) + srow) * Ec + h * DKc + sseg;
    const _Float16* Vg = VTh + ((size_t)(bh * DKc + srow)) * Sc + g * (Sc / 2) + sseg;

    // prime tile 0 of this group's half
    half8 kr0 = *(const half8*)Kg, kr1 = *(const half8*)(Kg + 8);
    half8 vr0 = *(const half8*)Vg, vr1 = *(const half8*)(Vg + 8);
    Kg += (size_t)BN * Ec; Vg += BN;
    *(half8*)&Kt[srow][sseg]     = kr0;
    *(half8*)&Kt[srow][sseg + 8] = kr1;

    floatx4 o[2][4] = {};
    float l_run[2] = {0.f, 0.f};   // per-lane: qrow = l16 of strip u

    for (int n = 0; n < NT; ++n) {
        __syncthreads();                               // (a)
        *(half8*)&Vt[srow][sseg]     = vr0;
        *(half8*)&Vt[srow][sseg + 8] = vr1;
        const bool more = (n + 1 < NT);
        if (more) {
            kr0 = *(const half8*)Kg; kr1 = *(const half8*)(Kg + 8);
            vr0 = *(const half8*)Vg; vr1 = *(const half8*)(Vg + 8);
            Kg += (size_t)BN * Ec; Vg += BN;
        }

        // ---- S^T = K Q^T: A = K-frag (m=key), B = Q-frag (n=qrow) ----
        floatx4 st[2][4];
#pragma unroll
        for (int i = 0; i < 4; ++i) {
            const half8 ak0 = *(const half8*)&Kt[i * 16 + l16][quad * 8];
            const half8 ak1 = *(const half8*)&Kt[i * 16 + l16][32 + quad * 8];
            const floatx4 z = {0.f, 0.f, 0.f, 0.f};
            st[0][i] = MFMA16(ak1, aq[0][1], MFMA16(ak0, aq[0][0], z));
            st[1][i] = MFMA16(ak1, aq[1][1], MFMA16(ak0, aq[1][0], z));
        }

        // ---- no-max softmax in exp2 domain; packed cvt + b64 Ps stores ----
#pragma unroll
        for (int u = 0; u < 2; ++u) {
            const int prow = wl * 32 + u * 16 + l16;
#pragma unroll
            for (int i = 0; i < 4; ++i) {
                const float p0 = __builtin_amdgcn_exp2f(st[u][i][0]);
                const float p1 = __builtin_amdgcn_exp2f(st[u][i][1]);
                const float p2 = __builtin_amdgcn_exp2f(st[u][i][2]);
                const float p3 = __builtin_amdgcn_exp2f(st[u][i][3]);
                l_run[u] += (p0 + p1) + (p2 + p3);
                auto lo = __builtin_amdgcn_cvt_pkrtz(p0, p1);
                auto hi = __builtin_amdgcn_cvt_pkrtz(p2, p3);
                half4 pk;
                pk.x = (_Float16)lo.x; pk.y = (_Float16)lo.y;
                pk.z = (_Float16)hi.x; pk.w = (_Float16)hi.y;
                *(half4*)&Pt[prow][i * 16 + quad * 4] = pk;
            }
        }
        __syncthreads();                               // (b)

        // ---- O += P V; bv shared by both strips ----
        half8 ap[2][2];
#pragma unroll
        for (int u = 0; u < 2; ++u) {
            const _Float16* pp = &Pt[wl * 32 + u * 16 + l16][quad * 8];
            ap[u][0] = *(const half8*)pp;
            ap[u][1] = *(const half8*)(pp + 32);
        }
#pragma unroll
        for (int jd = 0; jd < 4; ++jd) {
            const half8 bv0 = *(const half8*)&Vt[jd * 16 + l16][quad * 8];
            const half8 bv1 = *(const half8*)&Vt[jd * 16 + l16][32 + quad * 8];
#pragma unroll
            for (int u = 0; u < 2; ++u) {
                o[u][jd] = MFMA16(ap[u][0], bv0, o[u][jd]);
                o[u][jd] = MFMA16(ap[u][1], bv1, o[u][jd]);
            }
        }

        if (more) {
            *(half8*)&Kt[srow][sseg]     = kr0;
            *(half8*)&Kt[srow][sseg + 8] = kr1;
        }
    }

    // ---- wave-level row-sum reduce over quads (both groups) ----
#pragma unroll
    for (int u = 0; u < 2; ++u) {
        l_run[u] += __shfl_xor(l_run[u], 16);
        l_run[u] += __shfl_xor(l_run[u], 32);   // all lanes: sum for qrow=l16
    }

    // ---- cross-group combine via LDS (KV buffers are dead now) ----
    __syncthreads();                               // (c): all loop LDS reads done
    float* Os = (float*)KVs;                       // 128 x 64 fp32, ld 66 (33.8KB)
    if (g == 1) {
#pragma unroll
        for (int u = 0; u < 2; ++u) {
            if (quad == 0) Ls[wl * 32 + u * 16 + l16] = l_run[u];
#pragma unroll
            for (int jd = 0; jd < 4; ++jd)
#pragma unroll
                for (int r = 0; r < 4; ++r)
                    Os[(wl * 32 + u * 16 + quad * 4 + r) * 66 + jd * 16 + l16] = o[u][jd][r];
        }
    }
    __syncthreads();                               // (d)
    if (g == 0) {
        const float wmix = 1.f / (1.f + __expf(-qw[h]));
#pragma unroll
        for (int u = 0; u < 2; ++u)
#pragma unroll
            for (int r = 0; r < 4; ++r) {
                const int ml = wl * 32 + u * 16 + quad * 4 + r;
                const float l0 = __shfl(l_run[u], (lane & 48) | (quad * 4 + r));
                const float inv = 1.f / (l0 + Ls[ml]);
                const int m = q0 + ml;
                _Float16* mp = Mixh + (size_t)(b * Sc + m) * Ec + h * DKc;
#pragma unroll
                for (int jd = 0; jd < 4; ++jd) {
                    const float v = (o[u][jd][r] + Os[ml * 66 + jd * 16 + l16]) * inv;
                    mp[jd * 16 + l16] = (_Float16)(wmix * __sinf(v) + (1.f - wmix) * v);
                }
            }
    }
}

// ---------------------------------------------------------------------------
extern "C" void kernel_launch(void* const* d_in, const int* in_sizes, int n_in,
                              void* d_out, int out_size, void* d_ws, size_t ws_size,
                              hipStream_t stream)
{
    const float* x  = (const float*)d_in[0];
    const float* Wq = (const float*)d_in[1];
    const float* Wk = (const float*)d_in[2];
    const float* Wv = (const float*)d_in[3];
    const float* Wo = (const float*)d_in[4];
    const float* qw = (const float*)d_in[5];
    float* out = (float*)d_out;

    _Float16* hb   = (_Float16*)d_ws;
    _Float16* xh   = hb;
    _Float16* wqh  = hb + (size_t)4 * 1024 * 1024;
    _Float16* wkh  = hb + (size_t)5 * 1024 * 1024;
    _Float16* wvh  = hb + (size_t)6 * 1024 * 1024;
    _Float16* woh  = hb + (size_t)7 * 1024 * 1024;
    _Float16* Qh   = hb + (size_t)8 * 1024 * 1024;
    _Float16* Kh   = hb + (size_t)12 * 1024 * 1024;
    _Float16* VTh  = hb + (size_t)16 * 1024 * 1024;
    _Float16* mixh = hb + (size_t)20 * 1024 * 1024;

    convert_to_h<<<dim3(8192), dim3(256), 0, stream>>>(
        (const float4*)x, (const float4*)Wq, (const float4*)Wk,
        (const float4*)Wv, (const float4*)Wo, (half4*)hb);

    gemm_qkv_mfma<<<dim3(Ec / 128, Mc / 128, 3), dim3(256), 0, stream>>>(
        xh, wqh, wkh, wvh, Qh, Kh, VTh);

    flash_attn<<<dim3(Sc / 128, Bc * Hc), dim3(512), 0, stream>>>(
        Qh, Kh, VTh, qw, mixh);

    gemm_out_mfma<<<dim3(Ec / 64, Mc / 128), dim3(256), 0, stream>>>(
        mixh, woh, out);
}

// Round 2
// 188.781 us; speedup vs baseline: 1.0324x; 1.0124x over previous
//
#include <hip/hip_runtime.h>
#include <math.h>

// Problem constants (HybridAttention): B=2, S=2048, E=1024, H=16, Dk=64
constexpr int Ec  = 1024;
constexpr int Hc  = 16;
constexpr int DKc = 64;
constexpr int Bc  = 2;
constexpr int Sc  = 2048;
constexpr int Mc  = Bc * Sc;  // 4096 rows total

typedef _Float16 half8 __attribute__((ext_vector_type(8)));
typedef _Float16 half4 __attribute__((ext_vector_type(4)));
typedef float    floatx4  __attribute__((ext_vector_type(4)));
typedef float    floatx16 __attribute__((ext_vector_type(16)));
typedef unsigned int uint2v __attribute__((ext_vector_type(2)));
typedef unsigned int uint4v __attribute__((ext_vector_type(4)));

#define MFMA16(a, b, c) __builtin_amdgcn_mfma_f32_16x16x32_f16(a, b, c, 0, 0, 0)
#define MFMA32(a, b, c) __builtin_amdgcn_mfma_f32_32x32x16_f16(a, b, c, 0, 0, 0)

// async 16B global->LDS (dest = wave-uniform base + lane*16)
__device__ __forceinline__ void async_lds16(const _Float16* g, _Float16* l)
{
    __builtin_amdgcn_global_load_lds(
        (const __attribute__((address_space(1))) unsigned int*)g,
        (__attribute__((address_space(3))) unsigned int*)l, 16, 0, 0);
}

// pack two f32 -> u32 of two f16 (v_cvt_pkrtz_f16_f32)
__device__ __forceinline__ unsigned pkh2(float a, float b)
{
    return __builtin_bit_cast(unsigned, __builtin_amdgcn_cvt_pkrtz(a, b));
}

// ---------------------------------------------------------------------------
// fp32 -> fp16 convert: x (4M) | Wq | Wk | Wv | Wo (1M each) into one fp16 pool
// ---------------------------------------------------------------------------
__global__ __launch_bounds__(256)
void convert_to_h(const float4* __restrict__ x,
                  const float4* __restrict__ wq,
                  const float4* __restrict__ wk,
                  const float4* __restrict__ wv,
                  const float4* __restrict__ wo,
                  half4* __restrict__ dst)
{
    const int i = blockIdx.x * 256 + threadIdx.x;   // 0 .. 2M-1 (float4 units)
    const float4* src; int off;
    if      (i < 1048576) { src = x;  off = i; }
    else if (i < 1310720) { src = wq; off = i - 1048576; }
    else if (i < 1572864) { src = wk; off = i - 1310720; }
    else if (i < 1835008) { src = wv; off = i - 1572864; }
    else                  { src = wo; off = i - 1835008; }
    const float4 v = src[off];
    half4 o;
    o.x = (_Float16)v.x; o.y = (_Float16)v.y;
    o.z = (_Float16)v.z; o.w = (_Float16)v.w;
    dst[i] = o;
}

// ---------------------------------------------------------------------------
// fp16 MFMA GEMM core: C[128x128] = A[M,K] * W[N,K]^T tile, BK=64.
// Chunk-XOR swizzle on the per-lane GLOBAL address keeps global_load_lds's
// contiguous lane*16 dest while making frag reads conflict-free.
// ---------------------------------------------------------------------------
__device__ __forceinline__ void mfma_gemm_core64(const _Float16* __restrict__ A,
                                                 const _Float16* __restrict__ Bw,
                                                 int m0, int n0,
                                                 _Float16* As, _Float16* Bs,
                                                 floatx4 acc[4][4])
{
    const int tid  = threadIdx.x;
    const int wave = tid >> 6, lane = tid & 63;
    const int l16  = lane & 15, quad = lane >> 4;
    const int wrow = (wave >> 1) * 64, wcol = (wave & 1) * 64;

    const int srow8  = lane >> 3;
    const int schunk = (lane & 7) ^ (srow8 & 7);
    const _Float16* ga = A  + (size_t)(m0 + wave * 32 + srow8) * Ec + schunk * 8;
    const _Float16* gb = Bw + (size_t)(n0 + wave * 32 + srow8) * Ec + schunk * 8;
    _Float16* lA = As + (size_t)(wave * 32) * 64;
    _Float16* lB = Bs + (size_t)(wave * 32) * 64;

    for (int kt = 0; kt < Ec; kt += 64) {
#pragma unroll
        for (int c = 0; c < 4; ++c) {
            async_lds16(ga + (size_t)(c * 8) * Ec + kt, lA + c * 512);
            async_lds16(gb + (size_t)(c * 8) * Ec + kt, lB + c * 512);
        }
        __syncthreads();

        half8 af[4][2], bf[4][2];
#pragma unroll
        for (int i = 0; i < 4; ++i) {
            const int ra = wrow + i * 16 + l16;
            const int rb = wcol + i * 16 + l16;
#pragma unroll
            for (int kc = 0; kc < 2; ++kc) {
                af[i][kc] = *(const half8*)&As[ra * 64 + (((quad + kc * 4) ^ (ra & 7)) * 8)];
                bf[i][kc] = *(const half8*)&Bs[rb * 64 + (((quad + kc * 4) ^ (rb & 7)) * 8)];
            }
        }
#pragma unroll
        for (int i = 0; i < 4; ++i)
#pragma unroll
            for (int j = 0; j < 4; ++j) {
                acc[i][j] = MFMA16(af[i][0], bf[j][0], acc[i][j]);
                acc[i][j] = MFMA16(af[i][1], bf[j][1], acc[i][j]);
            }
        __syncthreads();
    }
}

// QKV projection: z=0 -> Qh (pre-scaled by 1/8 * log2(e) so flash can use raw
// v_exp_f32/exp2 with no per-score multiply), z=1 -> Kh, z=2 -> V^T [B,H,Dk,S]
__global__ __launch_bounds__(256)
void gemm_qkv_mfma(const _Float16* __restrict__ xh,
                   const _Float16* __restrict__ wqh,
                   const _Float16* __restrict__ wkh,
                   const _Float16* __restrict__ wvh,
                   _Float16* __restrict__ Qh,
                   _Float16* __restrict__ Kh,
                   _Float16* __restrict__ VTh)
{
    __shared__ __align__(16) _Float16 As[128 * 64];
    __shared__ __align__(16) _Float16 Bs[128 * 64];
    const int z = blockIdx.z;
    const _Float16* W = (z == 0) ? wqh : (z == 1) ? wkh : wvh;
    const int m0 = blockIdx.y * 128, n0 = blockIdx.x * 128;

    floatx4 acc[4][4] = {};
    mfma_gemm_core64(xh, W, m0, n0, As, Bs, acc);

    const int tid  = threadIdx.x;
    const int wave = tid >> 6, lane = tid & 63;
    const int l16  = lane & 15, quad = lane >> 4;
    const int wrow = (wave >> 1) * 64, wcol = (wave & 1) * 64;

    if (z == 2) {
        // VT[((b*H+h)*Dk+d)*S + s]: 4 consecutive m (=s) per lane -> half4 store
#pragma unroll
        for (int i = 0; i < 4; ++i)
#pragma unroll
            for (int j = 0; j < 4; ++j) {
                const int n  = n0 + wcol + j * 16 + l16;
                const int hh = n >> 6, d = n & 63;
                const int mb = m0 + wrow + i * 16 + quad * 4;
                const int bb = mb >> 11, s = mb & (Sc - 1);
                half4 pk;
#pragma unroll
                for (int r = 0; r < 4; ++r) pk[r] = (_Float16)acc[i][j][r];
                *(half4*)&VTh[((size_t)((bb * Hc + hh) * DKc + d)) * Sc + s] = pk;
            }
    } else {
        _Float16* out = (z == 0) ? Qh : Kh;
        // 0.125 * log2(e): scores come out in log2 domain for exp2 softmax
        const float scale = (z == 0) ? 0.18033688011112042f : 1.0f;
#pragma unroll
        for (int i = 0; i < 4; ++i)
#pragma unroll
            for (int j = 0; j < 4; ++j) {
                const int n = n0 + wcol + j * 16 + l16;
#pragma unroll
                for (int r = 0; r < 4; ++r) {
                    const int m = m0 + wrow + i * 16 + quad * 4 + r;
                    out[(size_t)m * Ec + n] = (_Float16)(acc[i][j][r] * scale);
                }
            }
    }
}

// Output projection: fp16 A (mix), fp16 Wo, fp32 out. 128x64 tile, BK=64.
__global__ __launch_bounds__(256)
void gemm_out_mfma(const _Float16* __restrict__ A,
                   const _Float16* __restrict__ W,
                   float* __restrict__ C)
{
    __shared__ __align__(16) _Float16 As[128 * 64];
    __shared__ __align__(16) _Float16 Bs[64 * 64];
    const int m0 = blockIdx.y * 128, n0 = blockIdx.x * 64;

    const int tid  = threadIdx.x;
    const int wave = tid >> 6, lane = tid & 63;
    const int l16  = lane & 15, quad = lane >> 4;
    const int wrow = (wave >> 1) * 64, wcol = (wave & 1) * 32;

    const int srow8  = lane >> 3;
    const int schunk = (lane & 7) ^ (srow8 & 7);
    const _Float16* ga = A + (size_t)(m0 + wave * 32 + srow8) * Ec + schunk * 8;
    const _Float16* gb = W + (size_t)(n0 + wave * 16 + srow8) * Ec + schunk * 8;
    _Float16* lA = As + (size_t)(wave * 32) * 64;
    _Float16* lB = Bs + (size_t)(wave * 16) * 64;

    floatx4 acc[4][2] = {};

    for (int kt = 0; kt < Ec; kt += 64) {
#pragma unroll
        for (int c = 0; c < 4; ++c)
            async_lds16(ga + (size_t)(c * 8) * Ec + kt, lA + c * 512);
#pragma unroll
        for (int c = 0; c < 2; ++c)
            async_lds16(gb + (size_t)(c * 8) * Ec + kt, lB + c * 512);
        __syncthreads();

        half8 af[4][2], bf[2][2];
#pragma unroll
        for (int i = 0; i < 4; ++i) {
            const int ra = wrow + i * 16 + l16;
#pragma unroll
            for (int kc = 0; kc < 2; ++kc)
                af[i][kc] = *(const half8*)&As[ra * 64 + (((quad + kc * 4) ^ (ra & 7)) * 8)];
        }
#pragma unroll
        for (int j = 0; j < 2; ++j) {
            const int rb = wcol + j * 16 + l16;
#pragma unroll
            for (int kc = 0; kc < 2; ++kc)
                bf[j][kc] = *(const half8*)&Bs[rb * 64 + (((quad + kc * 4) ^ (rb & 7)) * 8)];
        }
#pragma unroll
        for (int i = 0; i < 4; ++i)
#pragma unroll
            for (int j = 0; j < 2; ++j) {
                acc[i][j] = MFMA16(af[i][0], bf[j][0], acc[i][j]);
                acc[i][j] = MFMA16(af[i][1], bf[j][1], acc[i][j]);
            }
        __syncthreads();
    }

#pragma unroll
    for (int i = 0; i < 4; ++i)
#pragma unroll
        for (int j = 0; j < 2; ++j) {
            const int n = n0 + wcol + j * 16 + l16;
#pragma unroll
            for (int r = 0; r < 4; ++r) {
                const int m = m0 + wrow + i * 16 + quad * 4 + r;
                C[(size_t)m * Ec + n] = acc[i][j][r];
            }
        }
}

// ---------------------------------------------------------------------------
// Flash attention v3: 32x32x16 MFMA + in-register P (T12) + DMA staging.
//   - split-KV: 512 thr = 2 groups of 4 waves; group g owns KV half g.
//   - per wave: 32 q-rows. QK^T swapped (A=K, B=Q) so lane&31 = qrow and the
//     whole P-row is lane-local -> no Ps LDS, no barrier between QK and PV.
//     Exchange to PV A-fragments: 16 cvt_pkrtz + 8 permlane32_swap per tile.
//   - K/V staged by global_load_lds (chunk-XOR swizzle on global addr, linear
//     LDS dest), double-buffered -> ONE barrier per tile (was 2).
//   - no-max softmax in exp2 domain (log2e folded into Q scale upstream).
//   - combine: group 1 dumps O-acc + row sums to LDS (dead KV space), group 0
//     adds, normalizes, applies sin-mix, stores.
// ---------------------------------------------------------------------------
__global__ __launch_bounds__(512, 4)
void flash_attn(const _Float16* __restrict__ Qh,
                const _Float16* __restrict__ Kh,
                const _Float16* __restrict__ VTh,
                const float* __restrict__ qw,
                _Float16* __restrict__ Mixh)
{
    constexpr int BM = 128, BN = 64;
    constexpr int NT = (Sc / BN) / 2;                    // 16 tiles per group
    __shared__ __align__(16) _Float16 KV[2][2][2][64 * 64]; // [g][buf][K,V] 64KB
    __shared__ float Ls[2][128];                         // per-group row sums

    const int tid  = threadIdx.x;
    const int g    = tid >> 8;           // KV-half group
    const int wl   = (tid >> 6) & 3;     // wave within group
    const int lane = tid & 63;
    const int l31  = lane & 31, hi = lane >> 5;
    const int q0 = blockIdx.x * BM;
    const int bh = blockIdx.y;
    const int h  = bh & (Hc - 1), b = bh >> 4;

    // Q fragments: B-operand, col(qrow)=l31, k = ks*16 + hi*8 + j
    half8 aq[4];
    {
        const _Float16* qp = Qh + (size_t)(b * Sc + q0 + wl * 32 + l31) * Ec
                                + h * DKc + hi * 8;
#pragma unroll
        for (int ks = 0; ks < 4; ++ks) aq[ks] = *(const half8*)(qp + ks * 16);
    }

    // DMA staging: per wave 16 rows of K and 16 of V (2 calls each, 8 rows/call)
    const int srow   = lane >> 3;               // row within 8-row call
    const int schunk = (lane & 7) ^ srow;       // xor-swizzled global chunk
    const _Float16* Kg = Kh + (size_t)(b * Sc + g * (Sc / 2) + wl * 16 + srow) * Ec
                            + h * DKc + schunk * 8;
    const _Float16* Vg = VTh + ((size_t)(bh * DKc + wl * 16 + srow)) * Sc
                             + g * (Sc / 2) + schunk * 8;

    floatx16 o[2] = {};
    float l_run = 0.f;
    const int xk = l31 & 7;

    // prologue: stage tile 0 into buf 0
    {
        _Float16* kb = KV[g][0][0] + (wl * 16) * 64;
        _Float16* vb = KV[g][0][1] + (wl * 16) * 64;
        async_lds16(Kg, kb);
        async_lds16(Kg + (size_t)8 * Ec, kb + 8 * 64);
        async_lds16(Vg, vb);
        async_lds16(Vg + (size_t)8 * Sc, vb + 8 * 64);
    }
    __syncthreads();

    int cur = 0;
    for (int n = 0; n < NT; ++n) {
        // prefetch tile n+1 into the other buffer (lands before next barrier)
        if (n + 1 < NT) {
            _Float16* kb = KV[g][cur ^ 1][0] + (wl * 16) * 64;
            _Float16* vb = KV[g][cur ^ 1][1] + (wl * 16) * 64;
            const _Float16* kg = Kg + (size_t)(n + 1) * BN * Ec;
            const _Float16* vg = Vg + (size_t)(n + 1) * BN;
            async_lds16(kg, kb);
            async_lds16(kg + (size_t)8 * Ec, kb + 8 * 64);
            async_lds16(vg, vb);
            async_lds16(vg + (size_t)8 * Sc, vb + 8 * 64);
        }
        const _Float16* Kb = KV[g][cur][0];
        const _Float16* Vb = KV[g][cur][1];

#pragma unroll
        for (int t = 0; t < 2; ++t) {
            // ---- QK^T m-tile t: S^T[key][qrow], 4 k-steps ----
            floatx16 st = {};
#pragma unroll
            for (int ks = 0; ks < 4; ++ks) {
                const half8 ak = *(const half8*)
                    (Kb + (t * 32 + l31) * 64 + ((((ks << 1) | hi) ^ xk) << 3));
                st = MFMA32(ak, aq[ks], st);
            }
            // ---- softmax (exp2 domain), row-sum ----
            float p[16];
#pragma unroll
            for (int r = 0; r < 16; ++r) p[r] = __builtin_amdgcn_exp2f(st[r]);
#pragma unroll
            for (int r = 0; r < 16; ++r) l_run += p[r];
            // ---- pack + permlane32_swap -> PV A-fragments (ksteps 2t,2t+1) ----
            half8 pa[2];
#pragma unroll
            for (int e = 0; e < 2; ++e) {
                const unsigned X0 = pkh2(p[8 * e + 0], p[8 * e + 1]);
                const unsigned X1 = pkh2(p[8 * e + 2], p[8 * e + 3]);
                const unsigned Y0 = pkh2(p[8 * e + 4], p[8 * e + 5]);
                const unsigned Y1 = pkh2(p[8 * e + 6], p[8 * e + 7]);
                const uint2v s0 = __builtin_amdgcn_permlane32_swap(X0, Y0, false, false);
                const uint2v s1 = __builtin_amdgcn_permlane32_swap(X1, Y1, false, false);
                uint4v w;
                w.x = s0.x; w.y = s1.x; w.z = s0.y; w.w = s1.y;
                pa[e] = __builtin_bit_cast(half8, w);
            }
            // ---- O += P V for ksteps 2t, 2t+1 ----
#pragma unroll
            for (int dt = 0; dt < 2; ++dt)
#pragma unroll
                for (int e = 0; e < 2; ++e) {
                    const int ks = 2 * t + e;
                    const half8 bv = *(const half8*)
                        (Vb + (dt * 32 + l31) * 64 + ((((ks << 1) | hi) ^ xk) << 3));
                    o[dt] = MFMA32(pa[e], bv, o[dt]);
                }
        }
        __syncthreads();   // implies vmcnt(0): prefetch DMA retired, reads done
        cur ^= 1;
    }

    // ---- row sums: lanes l and l+32 hold complementary key halves ----
    l_run += __shfl_xor(l_run, 32);
    if (hi == 0) Ls[g][wl * 32 + l31] = l_run;

    // ---- cross-group combine via LDS (KV space is dead now) ----
    float* Os = (float*)&KV[0][0][0][0];   // 128 x 64 fp32, ld 66
    if (g == 1) {
#pragma unroll
        for (int dt = 0; dt < 2; ++dt)
#pragma unroll
            for (int r = 0; r < 16; ++r) {
                const int row = wl * 32 + (r & 3) + 8 * (r >> 2) + 4 * hi;
                Os[row * 66 + dt * 32 + l31] = o[dt][r];
            }
    }
    __syncthreads();
    if (g == 0) {
        const float wmix = 1.f / (1.f + __expf(-qw[h]));
#pragma unroll
        for (int r = 0; r < 16; ++r) {
            const int row = wl * 32 + (r & 3) + 8 * (r >> 2) + 4 * hi;
            const float inv = 1.f / (Ls[0][row] + Ls[1][row]);
            _Float16* mp = Mixh + (size_t)(b * Sc + q0 + row) * Ec + h * DKc;
#pragma unroll
            for (int dt = 0; dt < 2; ++dt) {
                const float v = (o[dt][r] + Os[row * 66 + dt * 32 + l31]) * inv;
                mp[dt * 32 + l31] = (_Float16)(wmix * __sinf(v) + (1.f - wmix) * v);
            }
        }
    }
}

// ---------------------------------------------------------------------------
extern "C" void kernel_launch(void* const* d_in, const int* in_sizes, int n_in,
                              void* d_out, int out_size, void* d_ws, size_t ws_size,
                              hipStream_t stream)
{
    const float* x  = (const float*)d_in[0];
    const float* Wq = (const float*)d_in[1];
    const float* Wk = (const float*)d_in[2];
    const float* Wv = (const float*)d_in[3];
    const float* Wo = (const float*)d_in[4];
    const float* qw = (const float*)d_in[5];
    float* out = (float*)d_out;

    _Float16* hb   = (_Float16*)d_ws;
    _Float16* xh   = hb;
    _Float16* wqh  = hb + (size_t)4 * 1024 * 1024;
    _Float16* wkh  = hb + (size_t)5 * 1024 * 1024;
    _Float16* wvh  = hb + (size_t)6 * 1024 * 1024;
    _Float16* woh  = hb + (size_t)7 * 1024 * 1024;
    _Float16* Qh   = hb + (size_t)8 * 1024 * 1024;
    _Float16* Kh   = hb + (size_t)12 * 1024 * 1024;
    _Float16* VTh  = hb + (size_t)16 * 1024 * 1024;
    _Float16* mixh = hb + (size_t)20 * 1024 * 1024;

    convert_to_h<<<dim3(8192), dim3(256), 0, stream>>>(
        (const float4*)x, (const float4*)Wq, (const float4*)Wk,
        (const float4*)Wv, (const float4*)Wo, (half4*)hb);

    gemm_qkv_mfma<<<dim3(Ec / 128, Mc / 128, 3), dim3(256), 0, stream>>>(
        xh, wqh, wkh, wvh, Qh, Kh, VTh);

    flash_attn<<<dim3(Sc / 128, Bc * Hc), dim3(512), 0, stream>>>(
        Qh, Kh, VTh, qw, mixh);

    gemm_out_mfma<<<dim3(Ec / 64, Mc / 128), dim3(256), 0, stream>>>(
        mixh, woh, out);
}